// Round 1
// baseline (973.003 us; speedup 1.0000x reference)
//
#include <hip/hip_runtime.h>

// Problem constants
#define B_   2
#define S_   2048
#define D_   2048
#define H_   16
#define HKV_ 4
#define HD_  128
#define SCALE_ 0.08838834764831845f  // 128^-0.5

typedef unsigned short u16;
typedef __attribute__((ext_vector_type(4))) float  f32x4;
typedef __attribute__((ext_vector_type(8))) __bf16 bf16x8;

__device__ __forceinline__ u16 f2b(float f) {
  unsigned int u = __builtin_bit_cast(unsigned int, f);
  u += 0x7fffu + ((u >> 16) & 1u);   // round-to-nearest-even
  return (u16)(u >> 16);
}

// ---------------- fp32 -> bf16 elementwise (x) ----------------
__global__ void k_f2b(const float* __restrict__ in, u16* __restrict__ out) {
  size_t i = (size_t)blockIdx.x * 256 + threadIdx.x;   // one float4 per thread
  float4 v = reinterpret_cast<const float4*>(in)[i];
  ushort4 o;
  o.x = f2b(v.x); o.y = f2b(v.y); o.z = f2b(v.z); o.w = f2b(v.w);
  reinterpret_cast<ushort4*>(out)[i] = o;
}

// ---------------- W[K][N] fp32 -> Wt[N][K] bf16 (tiled transpose) ----------------
__global__ void k_wT(const float* __restrict__ W, u16* __restrict__ Wt, int K, int N) {
  __shared__ float t[32][33];
  int n0 = blockIdx.x * 32, k0 = blockIdx.y * 32;
  int tx = threadIdx.x, ty = threadIdx.y;
  for (int j = ty; j < 32; j += 8)
    t[j][tx] = W[(size_t)(k0 + j) * N + n0 + tx];
  __syncthreads();
  for (int j = ty; j < 32; j += 8)
    Wt[(size_t)(n0 + j) * K + k0 + tx] = f2b(t[tx][j]);
}

// ---------------- GEMM: C[M][N] fp32 = A[M][K] bf16 * Bt[N][K] bf16 ----------------
// 128x128 tile, BK=64, 256 threads = 4 waves (2x2), wave computes 64x64 (4x4 frags)
__global__ __launch_bounds__(256, 2)
void k_gemm(const u16* __restrict__ A, const u16* __restrict__ Bt,
            float* __restrict__ C, int M, int N, int K) {
  __shared__ char smem[128 * 128 + 128 * 128];   // As 16KB + Bs 16KB (row = 64 bf16 = 128B)
  char* As = smem;
  char* Bs = smem + 128 * 128;
  const int tid = threadIdx.x;
  const int lane = tid & 63, wave = tid >> 6;
  const int l16 = lane & 15, lhi = lane >> 4;
  const int wm = (wave >> 1) * 64, wn = (wave & 1) * 64;
  const int bm = blockIdx.y, bn = blockIdx.x;
  const int ca = (tid & 7) * 16;   // byte chunk within 128B row
  const int ra = tid >> 3;         // 0..31
  const u16* Ab = A + (size_t)bm * 128 * K;
  const u16* Bb = Bt + (size_t)bn * 128 * K;
  f32x4 acc[4][4] = {};
  for (int k0 = 0; k0 < K; k0 += 64) {
    for (int p = 0; p < 4; ++p) {
      int row = ra + p * 32;
      int swz = ca ^ ((row & 7) << 4);
      const char* sa = (const char*)(Ab + (size_t)row * K + k0) + ca;
      const char* sb = (const char*)(Bb + (size_t)row * K + k0) + ca;
      *reinterpret_cast<int4*>(As + row * 128 + swz) = *reinterpret_cast<const int4*>(sa);
      *reinterpret_cast<int4*>(Bs + row * 128 + swz) = *reinterpret_cast<const int4*>(sb);
    }
    __syncthreads();
    for (int ks = 0; ks < 2; ++ks) {
      bf16x8 af[4], bfr[4];
      for (int f = 0; f < 4; ++f) {
        int m = wm + f * 16 + l16;
        af[f] = *reinterpret_cast<const bf16x8*>(As + m * 128 + ((ks * 64 + lhi * 16) ^ ((m & 7) << 4)));
        int n = wn + f * 16 + l16;
        bfr[f] = *reinterpret_cast<const bf16x8*>(Bs + n * 128 + ((ks * 64 + lhi * 16) ^ ((n & 7) << 4)));
      }
      for (int i = 0; i < 4; ++i)
        for (int j = 0; j < 4; ++j)
          acc[i][j] = __builtin_amdgcn_mfma_f32_16x16x32_bf16(af[i], bfr[j], acc[i][j], 0, 0, 0);
    }
    __syncthreads();
  }
  for (int i = 0; i < 4; ++i) {
    int m0 = bm * 128 + wm + i * 16 + lhi * 4;
    for (int j = 0; j < 4; ++j) {
      int n0 = bn * 128 + wn + j * 16 + l16;
      for (int r = 0; r < 4; ++r)
        C[(size_t)(m0 + r) * N + n0] = acc[i][j][r];
    }
  }
}

// ---------------- RoPE: pre[B*S][nh*128] fp32 -> outb[(b*nh+h)*S+s][128] bf16 ----------------
__global__ void k_rope(const float* __restrict__ pre, const float* __restrict__ cosT,
                       const float* __restrict__ sinT, u16* __restrict__ outb, int nh) {
  int idx = blockIdx.x;          // (b*S + s)*nh + h
  int h = idx % nh;
  int bs = idx / nh;
  int b = bs / S_, s = bs % S_;
  int d = threadIdx.x;           // 0..63
  const float* row = pre + (size_t)bs * (nh * HD_) + h * HD_;
  const float* cr = cosT + (size_t)bs * HD_;
  const float* sr = sinT + (size_t)bs * HD_;
  float v1 = row[d], v2 = row[d + 64];
  float c1 = cr[d], s1 = sr[d], c2 = cr[d + 64], s2 = sr[d + 64];
  u16* out = outb + (((size_t)b * nh + h) * S_ + s) * HD_;
  out[d]      = f2b(v1 * c1 - v2 * s1);
  out[d + 64] = f2b(v2 * c2 + v1 * s2);
}

// ---------------- V: vpre[B*S][512] fp32 -> vT[(b*HKV+h)*128+d][S] bf16 (tiled transpose) ----------------
__global__ void k_vT(const float* __restrict__ vpre, u16* __restrict__ vT) {
  __shared__ float t[32][33];
  int s0 = blockIdx.x * 32, d0 = blockIdx.y * 32;
  int bh = blockIdx.z;               // b*HKV + hk
  int b = bh >> 2, hk = bh & 3;
  int tx = threadIdx.x, ty = threadIdx.y;
  for (int j = ty; j < 32; j += 8)
    t[j][tx] = vpre[((size_t)b * S_ + s0 + j) * (HKV_ * HD_) + hk * HD_ + d0 + tx];
  __syncthreads();
  for (int j = ty; j < 32; j += 8)
    vT[((size_t)bh * HD_ + d0 + j) * S_ + s0 + tx] = f2b(t[tx][j]);
}

// ---------------- Attention: per block (b,h,qt): 64 q-rows, 4 waves x 16 rows ----------------
__global__ __launch_bounds__(256, 2)
void k_attn(const u16* __restrict__ qb, const u16* __restrict__ kb,
            const u16* __restrict__ vT, float* __restrict__ attn, u16* __restrict__ oh) {
  __shared__ u16 plds[4][16 * 32];   // per-wave p-tile bounce
  int bid = blockIdx.x;
  int qt = bid & 31, h = (bid >> 5) & 15, b = bid >> 9;
  int wave = threadIdx.x >> 6, lane = threadIdx.x & 63;
  int l16 = lane & 15, lhi = lane >> 4;
  int q0 = qt * 64 + wave * 16;
  int hk = h >> 2;  // jnp.repeat(k, 4, axis=1): head h -> kv head h/4
  const u16* Q  = qb + ((size_t)(b * H_ + h) * S_) * HD_;
  const u16* Kr = kb + ((size_t)(b * HKV_ + hk) * S_) * HD_;
  const u16* Vt = vT + ((size_t)(b * HKV_ + hk) * HD_) * S_;
  float* attnp = attn + (size_t)(b * H_ + h) * S_ * S_;

  bf16x8 qf[4];
  {
    const u16* qrow = Q + (size_t)(q0 + l16) * HD_ + lhi * 8;
    for (int kd = 0; kd < 4; ++kd)
      qf[kd] = *reinterpret_cast<const bf16x8*>(qrow + kd * 32);
  }
  const int kend = qt * 64 + 64;   // uniform across block (causal end of last row)

  auto qk = [&](int kt, f32x4& s0, f32x4& s1) {
    const u16* kp0 = Kr + (size_t)(kt + l16) * HD_ + lhi * 8;
    const u16* kp1 = kp0 + 16 * HD_;
    for (int kd = 0; kd < 4; ++kd) {
      bf16x8 kf0 = *reinterpret_cast<const bf16x8*>(kp0 + kd * 32);
      bf16x8 kf1 = *reinterpret_cast<const bf16x8*>(kp1 + kd * 32);
      s0 = __builtin_amdgcn_mfma_f32_16x16x32_bf16(qf[kd], kf0, s0, 0, 0, 0);
      s1 = __builtin_amdgcn_mfma_f32_16x16x32_bf16(qf[kd], kf1, s1, 0, 0, 0);
    }
  };

  float m[4], lsum[4];
  for (int r = 0; r < 4; ++r) { m[r] = -3.0e38f; lsum[r] = 0.f; }

  // pass 1: running max + denominator
  for (int kt = 0; kt < kend; kt += 32) {
    f32x4 s0 = {0.f, 0.f, 0.f, 0.f}, s1 = {0.f, 0.f, 0.f, 0.f};
    qk(kt, s0, s1);
    for (int r = 0; r < 4; ++r) {
      int row = q0 + lhi * 4 + r;
      float a  = s0[r] * SCALE_ + ((kt + l16)      > row ? -1e9f : 0.f);
      float b2 = s1[r] * SCALE_ + ((kt + 16 + l16) > row ? -1e9f : 0.f);
      float mx = fmaxf(a, b2);
      for (int off = 1; off < 16; off <<= 1) mx = fmaxf(mx, __shfl_xor(mx, off));
      float mn = fmaxf(m[r], mx);
      float e = __expf(a - mn) + __expf(b2 - mn);
      for (int off = 1; off < 16; off <<= 1) e += __shfl_xor(e, off);
      lsum[r] = lsum[r] * __expf(m[r] - mn) + e;
      m[r] = mn;
    }
  }
  float rinv[4];
  for (int r = 0; r < 4; ++r) rinv[r] = 1.f / lsum[r];

  // pass 2: normalized p -> attn out (fp32) + PV accumulate
  f32x4 oacc[8] = {};
  for (int kt = 0; kt < kend; kt += 32) {
    f32x4 s0 = {0.f, 0.f, 0.f, 0.f}, s1 = {0.f, 0.f, 0.f, 0.f};
    qk(kt, s0, s1);
    for (int r = 0; r < 4; ++r) {
      int row = q0 + lhi * 4 + r;
      float a  = s0[r] * SCALE_ + ((kt + l16)      > row ? -1e9f : 0.f);
      float b2 = s1[r] * SCALE_ + ((kt + 16 + l16) > row ? -1e9f : 0.f);
      float p0 = __expf(a - m[r]) * rinv[r];
      float p1 = __expf(b2 - m[r]) * rinv[r];
      attnp[(size_t)row * S_ + kt + l16]      = p0;
      attnp[(size_t)row * S_ + kt + 16 + l16] = p1;
      int rr = lhi * 4 + r;
      plds[wave][rr * 32 + l16]      = f2b(p0);
      plds[wave][rr * 32 + 16 + l16] = f2b(p1);
    }
    __syncthreads();   // uniform trip count across all 4 waves (kend is block-uniform)
    bf16x8 pa = *reinterpret_cast<const bf16x8*>(&plds[wave][l16 * 32 + lhi * 8]);
    for (int dt = 0; dt < 8; ++dt) {
      const u16* vp = Vt + (size_t)(dt * 16 + l16) * S_ + kt + lhi * 8;
      bf16x8 vf = *reinterpret_cast<const bf16x8*>(vp);
      oacc[dt] = __builtin_amdgcn_mfma_f32_16x16x32_bf16(pa, vf, oacc[dt], 0, 0, 0);
    }
    __syncthreads();
  }

  // zero-fill strictly-upper columns [kend, S) for this wave's 16 rows
  for (int rr = 0; rr < 16; ++rr) {
    size_t base = (size_t)(qt * 64 + wave * 16 + rr) * S_;
    for (int c = kend + lane * 4; c < S_; c += 256)
      *reinterpret_cast<float4*>(attnp + base + c) = make_float4(0.f, 0.f, 0.f, 0.f);
  }

  // write out heads: oh[b*S+row][h*128 + d] bf16
  for (int dt = 0; dt < 8; ++dt)
    for (int r = 0; r < 4; ++r) {
      int row = q0 + lhi * 4 + r;
      oh[((size_t)b * S_ + row) * (H_ * HD_) + h * HD_ + dt * 16 + l16] = f2b(oacc[dt][r]);
    }
}

extern "C" void kernel_launch(void* const* d_in, const int* in_sizes, int n_in,
                              void* d_out, int out_size, void* d_ws, size_t ws_size,
                              hipStream_t stream) {
  const float* x    = (const float*)d_in[0];
  const float* cosT = (const float*)d_in[1];
  const float* sinT = (const float*)d_in[2];
  // d_in[3] = attention_mask: pure causal, reconstructed in-kernel
  const float* Wq = (const float*)d_in[4];
  const float* Wk = (const float*)d_in[5];
  const float* Wv = (const float*)d_in[6];
  const float* Wo = (const float*)d_in[7];
  float* out  = (float*)d_out;
  float* attn = out + (size_t)B_ * S_ * D_;

  char* ws = (char*)d_ws;
  u16*   xb   = (u16*)(ws);                       // 16,777,216 B
  u16*   wqT  = (u16*)(ws + 16777216);            //  8,388,608
  u16*   wkT  = (u16*)(ws + 25165824);            //  2,097,152
  u16*   wvT  = (u16*)(ws + 27262976);            //  2,097,152
  u16*   woT  = (u16*)(ws + 29360128);            //  8,388,608
  float* qpre = (float*)(ws + 37748736);          // 33,554,432
  float* kpre = (float*)(ws + 71303168);          //  8,388,608
  float* vpre = (float*)(ws + 79691776);          //  8,388,608
  u16*   qb   = (u16*)(ws + 88080384);            // 16,777,216
  u16*   kb   = (u16*)(ws + 104857600);           //  4,194,304
  u16*   vT   = (u16*)(ws + 109051904);           //  4,194,304
  u16*   oh   = (u16*)(ws + 113246208);           // 16,777,216  (end ~130 MB)

  // 1) dtype prep
  k_f2b<<<8192, 256, 0, stream>>>(x, xb);                              // 8.4M elems / 4
  k_wT<<<dim3(64, 64), dim3(32, 8), 0, stream>>>(Wq, wqT, 2048, 2048);
  k_wT<<<dim3(16, 64), dim3(32, 8), 0, stream>>>(Wk, wkT, 2048, 512);
  k_wT<<<dim3(16, 64), dim3(32, 8), 0, stream>>>(Wv, wvT, 2048, 512);
  k_wT<<<dim3(64, 64), dim3(32, 8), 0, stream>>>(Wo, woT, 2048, 2048);

  // 2) QKV projections (fp32 out)
  k_gemm<<<dim3(16, 32), 256, 0, stream>>>(xb, wqT, qpre, 4096, 2048, 2048);
  k_gemm<<<dim3(4, 32), 256, 0, stream>>>(xb, wkT, kpre, 4096, 512, 2048);
  k_gemm<<<dim3(4, 32), 256, 0, stream>>>(xb, wvT, vpre, 4096, 512, 2048);

  // 3) RoPE + layout conversion to bf16
  k_rope<<<B_ * S_ * H_, 64, 0, stream>>>(qpre, cosT, sinT, qb, H_);
  k_rope<<<B_ * S_ * HKV_, 64, 0, stream>>>(kpre, cosT, sinT, kb, HKV_);
  k_vT<<<dim3(64, 4, B_ * HKV_), dim3(32, 8), 0, stream>>>(vpre, vT);

  // 4) attention (writes attn fp32 incl. upper-tri zeros, oh bf16)
  k_attn<<<B_ * H_ * (S_ / 64), 256, 0, stream>>>(qb, kb, vT, attn, oh);

  // 5) output projection
  k_gemm<<<dim3(16, 32), 256, 0, stream>>>(oh, woT, out, 4096, 2048, 2048);
}

// Round 2
// 685.427 us; speedup vs baseline: 1.4196x; 1.4196x over previous
//
#include <hip/hip_runtime.h>

// Problem constants
#define B_   2
#define S_   2048
#define D_   2048
#define H_   16
#define HKV_ 4
#define HD_  128
#define SCALE_ 0.08838834764831845f  // 128^-0.5

typedef unsigned short u16;
typedef __attribute__((ext_vector_type(4))) float  f32x4;
typedef __attribute__((ext_vector_type(8))) __bf16 bf16x8;

__device__ __forceinline__ u16 f2b(float f) {
  unsigned int u = __builtin_bit_cast(unsigned int, f);
  u += 0x7fffu + ((u >> 16) & 1u);   // round-to-nearest-even
  return (u16)(u >> 16);
}
__device__ __forceinline__ __bf16 f2bf(float f) {
  u16 b = f2b(f);
  return __builtin_bit_cast(__bf16, b);
}

// ---------------- fp32 -> bf16 elementwise (x) ----------------
__global__ void k_f2b(const float* __restrict__ in, u16* __restrict__ out) {
  size_t i = (size_t)blockIdx.x * 256 + threadIdx.x;   // one float4 per thread
  float4 v = reinterpret_cast<const float4*>(in)[i];
  ushort4 o;
  o.x = f2b(v.x); o.y = f2b(v.y); o.z = f2b(v.z); o.w = f2b(v.w);
  reinterpret_cast<ushort4*>(out)[i] = o;
}

// ---------------- W[K][N] fp32 -> Wt[N][K] bf16 (tiled transpose) ----------------
__global__ void k_wT(const float* __restrict__ W, u16* __restrict__ Wt, int K, int N) {
  __shared__ float t[32][33];
  int n0 = blockIdx.x * 32, k0 = blockIdx.y * 32;
  int tx = threadIdx.x, ty = threadIdx.y;
  for (int j = ty; j < 32; j += 8)
    t[j][tx] = W[(size_t)(k0 + j) * N + n0 + tx];
  __syncthreads();
  for (int j = ty; j < 32; j += 8)
    Wt[(size_t)(n0 + j) * K + k0 + tx] = f2b(t[tx][j]);
}

// ---------------- GEMM: C[M][N] fp32 = A[M][K] bf16 * Bt[N][K] bf16 ----------------
// 128x128 tile, BK=64, 256 threads = 4 waves (2x2), wave computes 64x64 (4x4 frags)
// Staging: global_load_lds width=16, linear LDS dest + inverse-swizzled global src
// (rule #21), read side applies the same XOR swizzle.
__global__ __launch_bounds__(256, 3)
void k_gemm(const u16* __restrict__ A, const u16* __restrict__ Bt,
            float* __restrict__ C, int M, int N, int K) {
  __shared__ char smem[128 * 128 + 128 * 128];   // As 16KB + Bs 16KB (row = 64 bf16 = 128B)
  char* As = smem;
  char* Bs = smem + 128 * 128;
  const int tid = threadIdx.x;
  const int lane = tid & 63, wave = tid >> 6;
  const int l16 = lane & 15, lhi = lane >> 4;
  const int wm = (wave >> 1) * 64, wn = (wave & 1) * 64;
  const int bm = blockIdx.y, bn = blockIdx.x;
  const u16* Ab = A + (size_t)bm * 128 * K;
  const u16* Bb = Bt + (size_t)bn * 128 * K;
  f32x4 acc[4][4] = {};
  for (int k0 = 0; k0 < K; k0 += 64) {
    // each wave stages 4 x 1KB blocks of A and of B (8 rows of 128B each)
    for (int p = 0; p < 4; ++p) {
      int r0 = wave * 32 + p * 8;
      int row = r0 + (lane >> 3);
      int src_off = ((lane & 7) * 16) ^ ((row & 7) << 4);   // inverse swizzle on source
      const char* ga = (const char*)(Ab + (size_t)row * K + k0) + src_off;
      const char* gb = (const char*)(Bb + (size_t)row * K + k0) + src_off;
      __builtin_amdgcn_global_load_lds(
          (const __attribute__((address_space(1))) void*)ga,
          (__attribute__((address_space(3))) void*)(As + r0 * 128), 16, 0, 0);
      __builtin_amdgcn_global_load_lds(
          (const __attribute__((address_space(1))) void*)gb,
          (__attribute__((address_space(3))) void*)(Bs + r0 * 128), 16, 0, 0);
    }
    __syncthreads();   // drains vmcnt (compiler emits waitcnt before s_barrier)
    for (int ks = 0; ks < 2; ++ks) {
      bf16x8 af[4], bfr[4];
      for (int f = 0; f < 4; ++f) {
        int m = wm + f * 16 + l16;
        af[f] = *reinterpret_cast<const bf16x8*>(As + m * 128 + ((ks * 64 + lhi * 16) ^ ((m & 7) << 4)));
        int n = wn + f * 16 + l16;
        bfr[f] = *reinterpret_cast<const bf16x8*>(Bs + n * 128 + ((ks * 64 + lhi * 16) ^ ((n & 7) << 4)));
      }
      for (int i = 0; i < 4; ++i)
        for (int j = 0; j < 4; ++j)
          acc[i][j] = __builtin_amdgcn_mfma_f32_16x16x32_bf16(af[i], bfr[j], acc[i][j], 0, 0, 0);
    }
    __syncthreads();
  }
  for (int i = 0; i < 4; ++i) {
    int m0 = bm * 128 + wm + i * 16 + lhi * 4;
    for (int j = 0; j < 4; ++j) {
      int n0 = bn * 128 + wn + j * 16 + l16;
      for (int r = 0; r < 4; ++r)
        C[(size_t)(m0 + r) * N + n0] = acc[i][j][r];
    }
  }
}

// ---------------- RoPE: pre[B*S][rowstride] fp32 -> outb[(b*nh+h)*S+s][128] bf16 ----------------
__global__ void k_rope(const float* __restrict__ pre, const float* __restrict__ cosT,
                       const float* __restrict__ sinT, u16* __restrict__ outb,
                       int nh, int rowstride) {
  int idx = blockIdx.x;          // (b*S + s)*nh + h
  int h = idx % nh;
  int bs = idx / nh;
  int b = bs / S_, s = bs % S_;
  int d = threadIdx.x;           // 0..63
  const float* row = pre + (size_t)bs * rowstride + h * HD_;
  const float* cr = cosT + (size_t)bs * HD_;
  const float* sr = sinT + (size_t)bs * HD_;
  float v1 = row[d], v2 = row[d + 64];
  float c1 = cr[d], s1 = sr[d], c2 = cr[d + 64], s2 = sr[d + 64];
  u16* out = outb + (((size_t)b * nh + h) * S_ + s) * HD_;
  out[d]      = f2b(v1 * c1 - v2 * s1);
  out[d + 64] = f2b(v2 * c2 + v1 * s2);
}

// ---------------- V: kvpre[B*S][1024] cols 512.. fp32 -> vT[(b*HKV+h)*128+d][S] bf16 ----------------
__global__ void k_vT(const float* __restrict__ kvpre, u16* __restrict__ vT) {
  __shared__ float t[32][33];
  int s0 = blockIdx.x * 32, d0 = blockIdx.y * 32;
  int bh = blockIdx.z;               // b*HKV + hk
  int b = bh >> 2, hk = bh & 3;
  int tx = threadIdx.x, ty = threadIdx.y;
  for (int j = ty; j < 32; j += 8)
    t[j][tx] = kvpre[((size_t)b * S_ + s0 + j) * 1024 + 512 + hk * HD_ + d0 + tx];
  __syncthreads();
  for (int j = ty; j < 32; j += 8)
    vT[((size_t)bh * HD_ + d0 + j) * S_ + s0 + tx] = f2b(t[tx][j]);
}

// ---------------- Attention ----------------
// One WAVE per 16-row q-tile: 4096 units = B*H*(S/16), packed 4/block (all 4 waves
// of a block share the same qt -> equal length). Units ordered longest-first
// (qt descending) for load balance. Per-lane online softmax (no shuffles in loop),
// one 16-lane reduce at the end; masked lanes cancel via exp(m_lane - m) -> 0.
__global__ __launch_bounds__(256, 4)
void k_attn(const u16* __restrict__ qb, const u16* __restrict__ kb,
            const u16* __restrict__ vT, float* __restrict__ attn, u16* __restrict__ oh) {
  __shared__ float pt_all[4][16 * 33];   // per-wave p-tile (padded rows: 33 floats)
  const int wave = threadIdx.x >> 6, lane = threadIdx.x & 63;
  const int l16 = lane & 15, lhi = lane >> 4;
  float* ptw = pt_all[wave];

  const int unit = blockIdx.x * 4 + wave;   // [0, 4096)
  const int qt = 127 - (unit >> 5);         // longest first
  const int bh = unit & 31;
  const int b = bh >> 4, h = bh & 15, hk = h >> 2;   // repeat(k,4): head h -> h/4
  const int q0 = qt * 16;
  const int kend = q0 + 16;
  const int lastkt = (kend - 1) & ~31;      // only the final 32-tile needs masking

  const u16* Q  = qb + ((size_t)(b * H_ + h) * S_) * HD_;
  const u16* Kr = kb + ((size_t)(b * HKV_ + hk) * S_) * HD_;
  const u16* Vt = vT + ((size_t)(b * HKV_ + hk) * HD_) * S_;
  float* attnp = attn + (size_t)(b * H_ + h) * S_ * S_;

  bf16x8 qf[4];
  {
    const u16* qrow = Q + (size_t)(q0 + l16) * HD_ + lhi * 8;
    #pragma unroll
    for (int kd = 0; kd < 4; ++kd)
      qf[kd] = *reinterpret_cast<const bf16x8*>(qrow + kd * 32);
  }

  auto qk = [&](int kt, f32x4& s0, f32x4& s1) {
    const u16* kp0 = Kr + (size_t)(kt + l16) * HD_ + lhi * 8;
    const u16* kp1 = kp0 + 16 * HD_;
    #pragma unroll
    for (int kd = 0; kd < 4; ++kd) {
      bf16x8 kf0 = *reinterpret_cast<const bf16x8*>(kp0 + kd * 32);
      bf16x8 kf1 = *reinterpret_cast<const bf16x8*>(kp1 + kd * 32);
      s0 = __builtin_amdgcn_mfma_f32_16x16x32_bf16(qf[kd], kf0, s0, 0, 0, 0);
      s1 = __builtin_amdgcn_mfma_f32_16x16x32_bf16(qf[kd], kf1, s1, 0, 0, 0);
    }
  };

  // ---- pass 1: per-lane online max/sum (no cross-lane ops in the loop) ----
  float m_l[4], l_l[4];
  #pragma unroll
  for (int r = 0; r < 4; ++r) { m_l[r] = -3.0e38f; l_l[r] = 0.f; }

  for (int kt = 0; kt <= lastkt; kt += 32) {
    f32x4 s0 = {0.f, 0.f, 0.f, 0.f}, s1 = {0.f, 0.f, 0.f, 0.f};
    qk(kt, s0, s1);
    bool mk = (kt == lastkt);   // wave-uniform branch
    #pragma unroll
    for (int r = 0; r < 4; ++r) {
      float a  = s0[r] * SCALE_;
      float b2 = s1[r] * SCALE_;
      if (mk) {
        int row = q0 + lhi * 4 + r;
        a  += (kt + l16)      > row ? -1e9f : 0.f;
        b2 += (kt + 16 + l16) > row ? -1e9f : 0.f;
      }
      float mn = fmaxf(m_l[r], fmaxf(a, b2));
      l_l[r] = l_l[r] * __expf(m_l[r] - mn) + __expf(a - mn) + __expf(b2 - mn);
      m_l[r] = mn;
    }
  }

  // ---- one cross-lane reduction (16-lane groups share lhi) ----
  float m[4], rinv[4];
  #pragma unroll
  for (int r = 0; r < 4; ++r) {
    float mm = m_l[r];
    for (int o = 1; o < 16; o <<= 1) mm = fmaxf(mm, __shfl_xor(mm, o));
    float ll = l_l[r] * __expf(m_l[r] - mm);   // fully-masked lanes -> exp(-1e9-mm)=0
    for (int o = 1; o < 16; o <<= 1) ll += __shfl_xor(ll, o);
    m[r] = mm;
    rinv[r] = 1.f / ll;
  }

  // ---- pass 2: p -> attn (fp32, coalesced via LDS) + PV accumulate ----
  f32x4 oacc[8] = {};
  for (int kt = 0; kt <= lastkt; kt += 32) {
    f32x4 s0 = {0.f, 0.f, 0.f, 0.f}, s1 = {0.f, 0.f, 0.f, 0.f};
    qk(kt, s0, s1);
    bool mk = (kt == lastkt);
    #pragma unroll
    for (int r = 0; r < 4; ++r) {
      float a  = s0[r] * SCALE_;
      float b2 = s1[r] * SCALE_;
      if (mk) {
        int row = q0 + lhi * 4 + r;
        a  += (kt + l16)      > row ? -1e9f : 0.f;
        b2 += (kt + 16 + l16) > row ? -1e9f : 0.f;
      }
      float p0 = __expf(a - m[r]) * rinv[r];
      float p1 = __expf(b2 - m[r]) * rinv[r];
      int rr = lhi * 4 + r;
      ptw[rr * 33 + l16]      = p0;
      ptw[rr * 33 + 16 + l16] = p1;
    }
    // coalesced attn write: 16 rows x 128B
    {
      int row2 = lane >> 2, c0 = (lane & 3) * 8;
      const float* src = ptw + row2 * 33 + c0;
      float4 w0, w1;
      w0.x = src[0]; w0.y = src[1]; w0.z = src[2]; w0.w = src[3];
      w1.x = src[4]; w1.y = src[5]; w1.z = src[6]; w1.w = src[7];
      float* dst = attnp + (size_t)(q0 + row2) * S_ + kt + c0;
      *reinterpret_cast<float4*>(dst)     = w0;
      *reinterpret_cast<float4*>(dst + 4) = w1;
    }
    // PV: A-frag = p-tile transpose read from LDS
    bf16x8 pa;
    #pragma unroll
    for (int j = 0; j < 8; ++j)
      pa[j] = f2bf(ptw[l16 * 33 + lhi * 8 + j]);
    #pragma unroll
    for (int dt = 0; dt < 8; ++dt) {
      const u16* vp = Vt + (size_t)(dt * 16 + l16) * S_ + kt + lhi * 8;
      bf16x8 vf = *reinterpret_cast<const bf16x8*>(vp);
      oacc[dt] = __builtin_amdgcn_mfma_f32_16x16x32_bf16(pa, vf, oacc[dt], 0, 0, 0);
    }
  }

  // ---- zero-fill columns [lastkt+32, S) ----
  {
    float4 z = make_float4(0.f, 0.f, 0.f, 0.f);
    int zr = q0 + (lane >> 2);
    for (int c = lastkt + 32 + (lane & 3) * 4; c < S_; c += 16)
      *reinterpret_cast<float4*>(attnp + (size_t)zr * S_ + c) = z;
  }

  // ---- write out heads: oh[b*S+row][h*128 + d] bf16 ----
  #pragma unroll
  for (int dt = 0; dt < 8; ++dt)
    #pragma unroll
    for (int r = 0; r < 4; ++r) {
      int row = q0 + lhi * 4 + r;
      oh[((size_t)b * S_ + row) * (H_ * HD_) + h * HD_ + dt * 16 + l16] = f2b(oacc[dt][r]);
    }
}

extern "C" void kernel_launch(void* const* d_in, const int* in_sizes, int n_in,
                              void* d_out, int out_size, void* d_ws, size_t ws_size,
                              hipStream_t stream) {
  const float* x    = (const float*)d_in[0];
  const float* cosT = (const float*)d_in[1];
  const float* sinT = (const float*)d_in[2];
  // d_in[3] = attention_mask: pure causal, reconstructed in-kernel
  const float* Wq = (const float*)d_in[4];
  const float* Wk = (const float*)d_in[5];
  const float* Wv = (const float*)d_in[6];
  const float* Wo = (const float*)d_in[7];
  float* out  = (float*)d_out;
  float* attn = out + (size_t)B_ * S_ * D_;

  char* ws = (char*)d_ws;
  u16*   xb    = (u16*)(ws);                       // 16,777,216 B
  u16*   wqT   = (u16*)(ws + 16777216);            //  8,388,608
  u16*   wkvT  = (u16*)(ws + 25165824);            //  4,194,304 (K rows 0..511, V rows 512..1023)
  u16*   woT   = (u16*)(ws + 29360128);            //  8,388,608
  float* qpre  = (float*)(ws + 37748736);          // 33,554,432
  float* kvpre = (float*)(ws + 71303168);          // 16,777,216
  u16*   qb    = (u16*)(ws + 88080384);            // 16,777,216
  u16*   kb    = (u16*)(ws + 104857600);           //  4,194,304
  u16*   vT    = (u16*)(ws + 109051904);           //  4,194,304
  u16*   oh    = (u16*)(ws + 113246208);           // 16,777,216  (end ~130 MB)

  // 1) dtype prep
  k_f2b<<<8192, 256, 0, stream>>>(x, xb);
  k_wT<<<dim3(64, 64), dim3(32, 8), 0, stream>>>(Wq, wqT, 2048, 2048);
  k_wT<<<dim3(16, 64), dim3(32, 8), 0, stream>>>(Wk, wkvT, 2048, 512);
  k_wT<<<dim3(16, 64), dim3(32, 8), 0, stream>>>(Wv, wkvT + (size_t)512 * 2048, 2048, 512);
  k_wT<<<dim3(64, 64), dim3(32, 8), 0, stream>>>(Wo, woT, 2048, 2048);

  // 2) projections: Q (N=2048) and fused K|V (N=1024)
  k_gemm<<<dim3(16, 32), 256, 0, stream>>>(xb, wqT, qpre, 4096, 2048, 2048);
  k_gemm<<<dim3(8, 32), 256, 0, stream>>>(xb, wkvT, kvpre, 4096, 1024, 2048);

  // 3) RoPE + layout conversion to bf16
  k_rope<<<B_ * S_ * H_, 64, 0, stream>>>(qpre, cosT, sinT, qb, H_, 2048);
  k_rope<<<B_ * S_ * HKV_, 64, 0, stream>>>(kvpre, cosT, sinT, kb, HKV_, 1024);
  k_vT<<<dim3(64, 4, B_ * HKV_), dim3(32, 8), 0, stream>>>(kvpre, vT);

  // 4) attention (writes attn fp32 incl. upper-tri zeros, oh bf16)
  k_attn<<<1024, 256, 0, stream>>>(qb, kb, vT, attn, oh);

  // 5) output projection
  k_gemm<<<dim3(16, 32), 256, 0, stream>>>(oh, woT, out, 4096, 2048, 2048);
}

// Round 3
// 680.155 us; speedup vs baseline: 1.4306x; 1.0078x over previous
//
#include <hip/hip_runtime.h>

// Problem constants
#define B_   2
#define S_   2048
#define D_   2048
#define H_   16
#define HKV_ 4
#define HD_  128
#define SCALE_ 0.08838834764831845f  // 128^-0.5

typedef unsigned short u16;
typedef __attribute__((ext_vector_type(4))) float  f32x4;
typedef __attribute__((ext_vector_type(8))) __bf16 bf16x8;

__device__ __forceinline__ u16 f2b(float f) {
  unsigned int u = __builtin_bit_cast(unsigned int, f);
  u += 0x7fffu + ((u >> 16) & 1u);   // round-to-nearest-even
  return (u16)(u >> 16);
}
__device__ __forceinline__ __bf16 f2bf(float f) {
  u16 b = f2b(f);
  return __builtin_bit_cast(__bf16, b);
}

// ---------------- fp32 -> bf16 elementwise (x) ----------------
__global__ void k_f2b(const float* __restrict__ in, u16* __restrict__ out) {
  size_t i = (size_t)blockIdx.x * 256 + threadIdx.x;   // one float4 per thread
  float4 v = reinterpret_cast<const float4*>(in)[i];
  ushort4 o;
  o.x = f2b(v.x); o.y = f2b(v.y); o.z = f2b(v.z); o.w = f2b(v.w);
  reinterpret_cast<ushort4*>(out)[i] = o;
}

// ---------------- W[K][N] fp32 -> Wt[N][K] bf16 (tiled transpose) ----------------
__global__ void k_wT(const float* __restrict__ W, u16* __restrict__ Wt, int K, int N) {
  __shared__ float t[32][33];
  int n0 = blockIdx.x * 32, k0 = blockIdx.y * 32;
  int tx = threadIdx.x, ty = threadIdx.y;
  for (int j = ty; j < 32; j += 8)
    t[j][tx] = W[(size_t)(k0 + j) * N + n0 + tx];
  __syncthreads();
  for (int j = ty; j < 32; j += 8)
    Wt[(size_t)(n0 + j) * K + k0 + tx] = f2b(t[tx][j]);
}

// ---------------- GEMM: C[M][N] fp32 = A[M][K] bf16 * Bt[N][K] bf16 ----------------
__global__ __launch_bounds__(256, 3)
void k_gemm(const u16* __restrict__ A, const u16* __restrict__ Bt,
            float* __restrict__ C, int M, int N, int K) {
  __shared__ char smem[128 * 128 + 128 * 128];   // As 16KB + Bs 16KB (row = 64 bf16 = 128B)
  char* As = smem;
  char* Bs = smem + 128 * 128;
  const int tid = threadIdx.x;
  const int lane = tid & 63, wave = tid >> 6;
  const int l16 = lane & 15, lhi = lane >> 4;
  const int wm = (wave >> 1) * 64, wn = (wave & 1) * 64;
  const int bm = blockIdx.y, bn = blockIdx.x;
  const u16* Ab = A + (size_t)bm * 128 * K;
  const u16* Bb = Bt + (size_t)bn * 128 * K;
  f32x4 acc[4][4] = {};
  for (int k0 = 0; k0 < K; k0 += 64) {
    for (int p = 0; p < 4; ++p) {
      int r0 = wave * 32 + p * 8;
      int row = r0 + (lane >> 3);
      int src_off = ((lane & 7) * 16) ^ ((row & 7) << 4);   // inverse swizzle on source
      const char* ga = (const char*)(Ab + (size_t)row * K + k0) + src_off;
      const char* gb = (const char*)(Bb + (size_t)row * K + k0) + src_off;
      __builtin_amdgcn_global_load_lds(
          (const __attribute__((address_space(1))) void*)ga,
          (__attribute__((address_space(3))) void*)(As + r0 * 128), 16, 0, 0);
      __builtin_amdgcn_global_load_lds(
          (const __attribute__((address_space(1))) void*)gb,
          (__attribute__((address_space(3))) void*)(Bs + r0 * 128), 16, 0, 0);
    }
    __syncthreads();
    for (int ks = 0; ks < 2; ++ks) {
      bf16x8 af[4], bfr[4];
      for (int f = 0; f < 4; ++f) {
        int m = wm + f * 16 + l16;
        af[f] = *reinterpret_cast<const bf16x8*>(As + m * 128 + ((ks * 64 + lhi * 16) ^ ((m & 7) << 4)));
        int n = wn + f * 16 + l16;
        bfr[f] = *reinterpret_cast<const bf16x8*>(Bs + n * 128 + ((ks * 64 + lhi * 16) ^ ((n & 7) << 4)));
      }
      for (int i = 0; i < 4; ++i)
        for (int j = 0; j < 4; ++j)
          acc[i][j] = __builtin_amdgcn_mfma_f32_16x16x32_bf16(af[i], bfr[j], acc[i][j], 0, 0, 0);
    }
    __syncthreads();
  }
  for (int i = 0; i < 4; ++i) {
    int m0 = bm * 128 + wm + i * 16 + lhi * 4;
    for (int j = 0; j < 4; ++j) {
      int n0 = bn * 128 + wn + j * 16 + l16;
      for (int r = 0; r < 4; ++r)
        C[(size_t)(m0 + r) * N + n0] = acc[i][j][r];
    }
  }
}

// ---------------- RoPE: pre[B*S][rowstride] fp32 -> outb[(b*nh+h)*S+s][128] bf16 ----------------
__global__ void k_rope(const float* __restrict__ pre, const float* __restrict__ cosT,
                       const float* __restrict__ sinT, u16* __restrict__ outb,
                       int nh, int rowstride) {
  int idx = blockIdx.x;          // (b*S + s)*nh + h
  int h = idx % nh;
  int bs = idx / nh;
  int b = bs / S_, s = bs % S_;
  int d = threadIdx.x;           // 0..63
  const float* row = pre + (size_t)bs * rowstride + h * HD_;
  const float* cr = cosT + (size_t)bs * HD_;
  const float* sr = sinT + (size_t)bs * HD_;
  float v1 = row[d], v2 = row[d + 64];
  float c1 = cr[d], s1 = sr[d], c2 = cr[d + 64], s2 = sr[d + 64];
  u16* out = outb + (((size_t)b * nh + h) * S_ + s) * HD_;
  out[d]      = f2b(v1 * c1 - v2 * s1);
  out[d + 64] = f2b(v2 * c2 + v1 * s2);
}

// ---------------- V: kvpre[B*S][1024] cols 512.. fp32 -> vT[(b*HKV+h)*128+d][S] bf16 ----------------
__global__ void k_vT(const float* __restrict__ kvpre, u16* __restrict__ vT) {
  __shared__ float t[32][33];
  int s0 = blockIdx.x * 32, d0 = blockIdx.y * 32;
  int bh = blockIdx.z;               // b*HKV + hk
  int b = bh >> 2, hk = bh & 3;
  int tx = threadIdx.x, ty = threadIdx.y;
  for (int j = ty; j < 32; j += 8)
    t[j][tx] = kvpre[((size_t)b * S_ + s0 + j) * 1024 + 512 + hk * HD_ + d0 + tx];
  __syncthreads();
  for (int j = ty; j < 32; j += 8)
    vT[((size_t)bh * HD_ + d0 + j) * S_ + s0 + tx] = f2b(t[tx][j]);
}

// ---------------- Attention ----------------
// One BLOCK per 16-row q-tile (4096 blocks, longest-first). The block's 4 waves
// split the k-tiles round-robin (wave w: tiles w, w+4, ...). Phase A: partial
// online (m,l) per wave -> LDS combine. Phase B: re-sweep, write normalized attn
// + PV partial; PV combined via LDS in 4 rounds. Zero-fill split 4 rows/wave.
__global__ __launch_bounds__(256, 6)
void k_attn(const u16* __restrict__ qb, const u16* __restrict__ kb,
            const u16* __restrict__ vT, float* __restrict__ attn, u16* __restrict__ oh) {
  __shared__ float pt_all[4][16 * 33];    // per-wave p-tile (padded rows)
  __shared__ float red_m[4][16], red_l[4][16];
  __shared__ f32x4 comb[4][2][64];        // PV combine: [wave][dt-half][lane]

  const int wave = threadIdx.x >> 6, lane = threadIdx.x & 63;
  const int l16 = lane & 15, lhi = lane >> 4;
  float* ptw = pt_all[wave];

  const int bid = blockIdx.x;
  const int qt = 127 - (bid >> 5);          // longest first
  const int bh = bid & 31;
  const int b = bh >> 4, h = bh & 15, hk = h >> 2;   // repeat(k,4): head h -> h/4
  const int q0 = qt * 16;
  const int nt = (qt + 2) >> 1;             // number of 32-key tiles (= ceil((q0+16)/32))
  const int tmask = nt - 1;                 // only tile needing causal mask

  const u16* Q  = qb + ((size_t)(b * H_ + h) * S_) * HD_;
  const u16* Kr = kb + ((size_t)(b * HKV_ + hk) * S_) * HD_;
  const u16* Vt = vT + ((size_t)(b * HKV_ + hk) * HD_) * S_;
  float* attnp = attn + (size_t)(b * H_ + h) * S_ * S_;

  bf16x8 qf[4];
  {
    const u16* qrow = Q + (size_t)(q0 + l16) * HD_ + lhi * 8;
    #pragma unroll
    for (int kd = 0; kd < 4; ++kd)
      qf[kd] = *reinterpret_cast<const bf16x8*>(qrow + kd * 32);
  }

  auto qk = [&](int kt, f32x4& s0, f32x4& s1) {
    const u16* kp0 = Kr + (size_t)(kt + l16) * HD_ + lhi * 8;
    const u16* kp1 = kp0 + 16 * HD_;
    #pragma unroll
    for (int kd = 0; kd < 4; ++kd) {
      bf16x8 kf0 = *reinterpret_cast<const bf16x8*>(kp0 + kd * 32);
      bf16x8 kf1 = *reinterpret_cast<const bf16x8*>(kp1 + kd * 32);
      s0 = __builtin_amdgcn_mfma_f32_16x16x32_bf16(qf[kd], kf0, s0, 0, 0, 0);
      s1 = __builtin_amdgcn_mfma_f32_16x16x32_bf16(qf[kd], kf1, s1, 0, 0, 0);
    }
  };

  // ---- phase A: per-wave partial online max/sum over its tile subset ----
  float m_l[4], l_l[4];
  #pragma unroll
  for (int r = 0; r < 4; ++r) { m_l[r] = -3.0e38f; l_l[r] = 0.f; }

  for (int t = wave; t < nt; t += 4) {
    int kt = t * 32;
    f32x4 s0 = {0.f, 0.f, 0.f, 0.f}, s1 = {0.f, 0.f, 0.f, 0.f};
    qk(kt, s0, s1);
    bool mk = (t == tmask);   // wave-uniform
    #pragma unroll
    for (int r = 0; r < 4; ++r) {
      float a  = s0[r] * SCALE_;
      float b2 = s1[r] * SCALE_;
      if (mk) {
        int row = q0 + lhi * 4 + r;
        a  += (kt + l16)      > row ? -1e9f : 0.f;
        b2 += (kt + 16 + l16) > row ? -1e9f : 0.f;
      }
      float mn = fmaxf(m_l[r], fmaxf(a, b2));
      l_l[r] = l_l[r] * __expf(m_l[r] - mn) + __expf(a - mn) + __expf(b2 - mn);
      m_l[r] = mn;
    }
  }

  // 16-lane reduce within wave, then cross-wave combine via LDS
  #pragma unroll
  for (int r = 0; r < 4; ++r) {
    float mm = m_l[r];
    for (int o = 1; o < 16; o <<= 1) mm = fmaxf(mm, __shfl_xor(mm, o));
    float ll = l_l[r] * __expf(m_l[r] - mm);   // empty/masked lanes -> 0
    for (int o = 1; o < 16; o <<= 1) ll += __shfl_xor(ll, o);
    if (l16 == 0) { red_m[wave][lhi * 4 + r] = mm; red_l[wave][lhi * 4 + r] = ll; }
  }
  __syncthreads();
  float m[4], rinv[4];
  #pragma unroll
  for (int r = 0; r < 4; ++r) {
    int rw = lhi * 4 + r;
    float m0w = red_m[0][rw], m1w = red_m[1][rw], m2w = red_m[2][rw], m3w = red_m[3][rw];
    float mm = fmaxf(fmaxf(m0w, m1w), fmaxf(m2w, m3w));
    float ll = red_l[0][rw] * __expf(m0w - mm) + red_l[1][rw] * __expf(m1w - mm)
             + red_l[2][rw] * __expf(m2w - mm) + red_l[3][rw] * __expf(m3w - mm);
    m[r] = mm;
    rinv[r] = 1.f / ll;
  }

  // ---- phase B: re-sweep own tiles: normalized attn write + PV partial ----
  f32x4 oacc[8] = {};
  for (int t = wave; t < nt; t += 4) {
    int kt = t * 32;
    f32x4 s0 = {0.f, 0.f, 0.f, 0.f}, s1 = {0.f, 0.f, 0.f, 0.f};
    qk(kt, s0, s1);
    bool mk = (t == tmask);
    #pragma unroll
    for (int r = 0; r < 4; ++r) {
      float a  = s0[r] * SCALE_;
      float b2 = s1[r] * SCALE_;
      if (mk) {
        int row = q0 + lhi * 4 + r;
        a  += (kt + l16)      > row ? -1e9f : 0.f;
        b2 += (kt + 16 + l16) > row ? -1e9f : 0.f;
      }
      float p0 = __expf(a - m[r]) * rinv[r];
      float p1 = __expf(b2 - m[r]) * rinv[r];
      int rr = lhi * 4 + r;
      ptw[rr * 33 + l16]      = p0;
      ptw[rr * 33 + 16 + l16] = p1;
    }
    // coalesced attn write: 16 rows x 128B (wave-local LDS; no barrier needed)
    {
      int row2 = lane >> 2, c0 = (lane & 3) * 8;
      const float* src = ptw + row2 * 33 + c0;
      float4 w0, w1;
      w0.x = src[0]; w0.y = src[1]; w0.z = src[2]; w0.w = src[3];
      w1.x = src[4]; w1.y = src[5]; w1.z = src[6]; w1.w = src[7];
      float* dst = attnp + (size_t)(q0 + row2) * S_ + kt + c0;
      *reinterpret_cast<float4*>(dst)     = w0;
      *reinterpret_cast<float4*>(dst + 4) = w1;
    }
    // PV: A-frag = p-tile transpose read from LDS
    bf16x8 pa;
    #pragma unroll
    for (int j = 0; j < 8; ++j)
      pa[j] = f2bf(ptw[l16 * 33 + lhi * 8 + j]);
    #pragma unroll
    for (int dt = 0; dt < 8; ++dt) {
      const u16* vp = Vt + (size_t)(dt * 16 + l16) * S_ + kt + lhi * 8;
      bf16x8 vf = *reinterpret_cast<const bf16x8*>(vp);
      oacc[dt] = __builtin_amdgcn_mfma_f32_16x16x32_bf16(pa, vf, oacc[dt], 0, 0, 0);
    }
  }

  // ---- PV combine across waves (4 rounds of 2 dt) + oh write ----
  for (int rd = 0; rd < 4; ++rd) {
    comb[wave][0][lane] = oacc[rd * 2];
    comb[wave][1][lane] = oacc[rd * 2 + 1];
    __syncthreads();
    if (threadIdx.x < 128) {
      int half = threadIdx.x >> 6, ln = threadIdx.x & 63;
      f32x4 s = comb[0][half][ln] + comb[1][half][ln] + comb[2][half][ln] + comb[3][half][ln];
      int dt = rd * 2 + half;
      int c16 = ln & 15, rh = ln >> 4;
      #pragma unroll
      for (int r = 0; r < 4; ++r) {
        int row = q0 + rh * 4 + r;
        oh[((size_t)b * S_ + row) * (H_ * HD_) + h * HD_ + dt * 16 + c16] = f2b(s[r]);
      }
    }
    __syncthreads();
  }

  // ---- zero-fill columns [32*nt, S): 4 rows per wave ----
  {
    float4 z = make_float4(0.f, 0.f, 0.f, 0.f);
    int zrow = q0 + wave * 4 + lhi;
    for (int c = 32 * nt + l16 * 4; c < S_; c += 64)
      *reinterpret_cast<float4*>(attnp + (size_t)zrow * S_ + c) = z;
  }
}

extern "C" void kernel_launch(void* const* d_in, const int* in_sizes, int n_in,
                              void* d_out, int out_size, void* d_ws, size_t ws_size,
                              hipStream_t stream) {
  const float* x    = (const float*)d_in[0];
  const float* cosT = (const float*)d_in[1];
  const float* sinT = (const float*)d_in[2];
  // d_in[3] = attention_mask: pure causal, reconstructed in-kernel
  const float* Wq = (const float*)d_in[4];
  const float* Wk = (const float*)d_in[5];
  const float* Wv = (const float*)d_in[6];
  const float* Wo = (const float*)d_in[7];
  float* out  = (float*)d_out;
  float* attn = out + (size_t)B_ * S_ * D_;

  char* ws = (char*)d_ws;
  u16*   xb    = (u16*)(ws);                       // 16,777,216 B
  u16*   wqT   = (u16*)(ws + 16777216);            //  8,388,608
  u16*   wkvT  = (u16*)(ws + 25165824);            //  4,194,304 (K rows 0..511, V rows 512..1023)
  u16*   woT   = (u16*)(ws + 29360128);            //  8,388,608
  float* qpre  = (float*)(ws + 37748736);          // 33,554,432
  float* kvpre = (float*)(ws + 71303168);          // 16,777,216
  u16*   qb    = (u16*)(ws + 88080384);            // 16,777,216
  u16*   kb    = (u16*)(ws + 104857600);           //  4,194,304
  u16*   vT    = (u16*)(ws + 109051904);           //  4,194,304
  u16*   oh    = (u16*)(ws + 113246208);           // 16,777,216  (end ~130 MB)

  // 1) dtype prep
  k_f2b<<<8192, 256, 0, stream>>>(x, xb);
  k_wT<<<dim3(64, 64), dim3(32, 8), 0, stream>>>(Wq, wqT, 2048, 2048);
  k_wT<<<dim3(16, 64), dim3(32, 8), 0, stream>>>(Wk, wkvT, 2048, 512);
  k_wT<<<dim3(16, 64), dim3(32, 8), 0, stream>>>(Wv, wkvT + (size_t)512 * 2048, 2048, 512);
  k_wT<<<dim3(64, 64), dim3(32, 8), 0, stream>>>(Wo, woT, 2048, 2048);

  // 2) projections: Q (N=2048) and fused K|V (N=1024)
  k_gemm<<<dim3(16, 32), 256, 0, stream>>>(xb, wqT, qpre, 4096, 2048, 2048);
  k_gemm<<<dim3(8, 32), 256, 0, stream>>>(xb, wkvT, kvpre, 4096, 1024, 2048);

  // 3) RoPE + layout conversion to bf16
  k_rope<<<B_ * S_ * H_, 64, 0, stream>>>(qpre, cosT, sinT, qb, H_, 2048);
  k_rope<<<B_ * S_ * HKV_, 64, 0, stream>>>(kvpre, cosT, sinT, kb, HKV_, 1024);
  k_vT<<<dim3(64, 4, B_ * HKV_), dim3(32, 8), 0, stream>>>(kvpre, vT);

  // 4) attention (writes attn fp32 incl. upper-tri zeros, oh bf16)
  k_attn<<<4096, 256, 0, stream>>>(qb, kb, vT, attn, oh);

  // 5) output projection
  k_gemm<<<dim3(16, 32), 256, 0, stream>>>(oh, woT, out, 4096, 2048, 2048);
}